// Round 10
// baseline (136.726 us; speedup 1.0000x reference)
//
#include <hip/hip_runtime.h>
#include <cstdint>

#define BB 2
#define NN 16384
#define MM 2048
#define CC 64
#define SS 32
#define WPB 4  // waves (queries) per block

// ws layout: feat_t [0, 8388608) | idx_all [8388608, 8912896) | maxj cell [8912896, +4)

__device__ __forceinline__ float dist2(float qx, float qy, float qz,
                                       float px, float py, float pz) {
    // Match reference rounding: explicit mul/add, no FMA contraction.
    // Verified exact (absmax=0.0) in Rounds 4/8/9 — do not change.
    float dx = __fsub_rn(qx, px), dy = __fsub_rn(qy, py), dz = __fsub_rn(qz, pz);
    return __fadd_rn(__fadd_rn(__fmul_rn(dx, dx), __fmul_rn(dy, dy)), __fmul_rn(dz, dz));
}

// Kernel 1: ballot scan (verified semantics), native xyz loads (L2-resident).
// Writes cnt (float) to out[bm], resolved slot indices to idx_all, and a safe
// upper bound on the max scanned index via atomicMax (poison 0xAAAAAAAA is a
// negative int, so max recovers).
__global__ __launch_bounds__(64 * WPB) void scan_kernel(
    const float* __restrict__ xyz, const float* __restrict__ new_xyz,
    int* __restrict__ idx_all, int* __restrict__ maxj_cell,
    float* __restrict__ out) {
    constexpr float R_IN2 = 0.05f * 0.05f;
    constexpr float R_OUT2 = 0.2f * 0.2f;
    __shared__ int idxS[WPB][SS];

    int lane = threadIdx.x & 63;
    int w = threadIdx.x >> 6;
    int bm = blockIdx.x * WPB + w;
    int b = bm >> 11;

    float qx = new_xyz[(size_t)bm * 3 + 0];
    float qy = new_xyz[(size_t)bm * 3 + 1];
    float qz = new_xyz[(size_t)bm * 3 + 2];

    if (lane == 0) idxS[w][0] = 0;  // default when zero matches

    unsigned long long below = (1ull << lane) - 1ull;
    int cnt = 0;
    int j_exit = NN;
    for (int j0 = 0; j0 < NN; j0 += 256) {
        float px[4], py[4], pz[4];
        const float* pp = xyz + ((size_t)(b * NN + j0 + lane)) * 3;
#pragma unroll
        for (int u = 0; u < 4; ++u) {
            px[u] = pp[u * 192 + 0];
            py[u] = pp[u * 192 + 1];
            pz[u] = pp[u * 192 + 2];
        }
#pragma unroll
        for (int u = 0; u < 4; ++u) {
            float d2 = dist2(qx, qy, qz, px[u], py[u], pz[u]);
            bool inshell = (d2 >= R_IN2) && (d2 < R_OUT2);
            unsigned long long mk = __ballot(inshell);
            if (inshell) {
                int r = cnt + __popcll(mk & below);
                if (r < SS) idxS[w][r] = j0 + u * 64 + lane;
            }
            cnt += __popcll(mk);
        }
        if (cnt >= SS) { j_exit = j0 + 256; break; }  // wave-uniform
    }
    if (cnt > SS) cnt = SS;
    if (lane == 0) {
        out[bm] = (float)cnt;  // idx_cnt as float
        atomicMax(maxj_cell, j_exit);
    }
    if (lane < SS) {
        int j = (lane < cnt) ? idxS[w][lane] : idxS[w][0];
        idx_all[bm * SS + lane] = j;  // resolved (overflow slots = first match)
    }
}

// Kernel 2: transpose features (B,C,N)->(B,N,C), bounded by maxj — blocks
// whose row range was never scanned exit immediately.
__global__ __launch_bounds__(256) void transpose_bounded(
    const float* __restrict__ f, float* __restrict__ ft,
    const int* __restrict__ maxj_cell) {
    int limit = *maxj_cell;
    int bid = blockIdx.x;
    int n0 = (bid & 511) * 32;          // N/32 = 512 tiles
    if (n0 >= limit) return;            // row tile never referenced
    int c0 = ((bid >> 9) & 1) * 32;     // C/32 = 2 tiles
    int b = bid >> 10;                  // B = 2
    __shared__ float tile[32][33];
    int tx = threadIdx.x & 31, ty = threadIdx.x >> 5;  // (32,8)
#pragma unroll
    for (int k = 0; k < 32; k += 8)
        tile[ty + k][tx] = f[((size_t)(b * CC + c0 + ty + k)) * NN + n0 + tx];
    __syncthreads();
#pragma unroll
    for (int k = 0; k < 32; k += 8)
        ft[((size_t)(b * NN + n0 + ty + k)) * CC + c0 + tx] = tile[tx][ty + k];
}

// Kernel 3: group. Reads pre-resolved indices; phase 2 ILP gather from feat_t
// rows staged in LDS; phase 3 float4 channel-major coalesced stores.
// (Verified phase code from Round 9, with cnt-fallback already resolved.)
__global__ __launch_bounds__(64 * WPB) void group_kernel(
    const float* __restrict__ xyz, const float* __restrict__ new_xyz,
    const float* __restrict__ feat_t, const int* __restrict__ idx_all,
    float* __restrict__ out) {
    __shared__ int idxS[WPB][SS];
    __shared__ float fbuf[WPB][SS][CC + 4];  // 16B-aligned rows (stride 68)

    int lane = threadIdx.x & 63;
    int w = threadIdx.x >> 6;
    int bm = blockIdx.x * WPB + w;
    int b = bm >> 11;
    int m = bm & 2047;

    if (lane < SS) idxS[w][lane] = idx_all[bm * SS + lane];
    // wave-internal lockstep: LDS write then dependent reads (compiler waitcnt)

    float* gout = out + BB * MM;

    // Phase 2: gather 32 slots x 64 ch; all 8 float4 loads in flight.
    int s4 = lane >> 4, c4 = lane & 15;
    int jj[8];
#pragma unroll
    for (int it = 0; it < 8; ++it) jj[it] = idxS[w][it * 4 + s4];
    float4 vv[8];
#pragma unroll
    for (int it = 0; it < 8; ++it)
        vv[it] = ((const float4*)(feat_t + ((size_t)b * NN + jj[it]) * CC))[c4];
#pragma unroll
    for (int it = 0; it < 8; ++it)
        *((float4*)&fbuf[w][it * 4 + s4][c4 * 4]) = vv[it];

    // xyz channels 0..2: grouped_xyz = xyz[j] - new_xyz[m]
    {
        int s = lane & 31, half = lane >> 5;
        int j = idxS[w][s];
        const float* pp = xyz + ((size_t)(b * NN) + j) * 3;
        float px = pp[0], py = pp[1], pz = pp[2];
        float qx = new_xyz[(size_t)bm * 3 + 0];
        float qy = new_xyz[(size_t)bm * 3 + 1];
        float qz = new_xyz[(size_t)bm * 3 + 2];
        float v01 = half ? __fsub_rn(py, qy) : __fsub_rn(px, qx);
        gout[((size_t)(b * 67 + half) * MM + m) * SS + s] = v01;
        if (half == 0) {
            gout[((size_t)(b * 67 + 2) * MM + m) * SS + s] = __fsub_rn(pz, qz);
        }
    }

    // Phase 3: feature channels via float4 stores (8 instructions total).
    {
        int ch8 = lane >> 3, sg = lane & 7;
#pragma unroll
        for (int it = 0; it < 8; ++it) {
            int ch = it * 8 + ch8;
            float4 v = make_float4(fbuf[w][sg * 4 + 0][ch], fbuf[w][sg * 4 + 1][ch],
                                   fbuf[w][sg * 4 + 2][ch], fbuf[w][sg * 4 + 3][ch]);
            *((float4*)&gout[((size_t)(b * 67 + 3 + ch) * MM + m) * SS + sg * 4]) = v;
        }
    }
}

// Fallback (ws too small): monolithic verified-semantics kernel, native layouts.
__global__ __launch_bounds__(64 * WPB) void query_group_fallback(
    const float* __restrict__ xyz, const float* __restrict__ new_xyz,
    const float* __restrict__ features, float* __restrict__ out) {
    constexpr float R_IN2 = 0.05f * 0.05f;
    constexpr float R_OUT2 = 0.2f * 0.2f;
    __shared__ int idxS[WPB][SS];

    int lane = threadIdx.x & 63;
    int w = threadIdx.x >> 6;
    int bm = blockIdx.x * WPB + w;
    int b = bm >> 11;
    int m = bm & 2047;

    float qx = new_xyz[(size_t)bm * 3 + 0];
    float qy = new_xyz[(size_t)bm * 3 + 1];
    float qz = new_xyz[(size_t)bm * 3 + 2];

    if (lane == 0) idxS[w][0] = 0;

    unsigned long long below = (1ull << lane) - 1ull;
    int cnt = 0;
    for (int j0 = 0; j0 < NN; j0 += 256) {
        float px[4], py[4], pz[4];
        const float* pp = xyz + ((size_t)(b * NN + j0 + lane)) * 3;
#pragma unroll
        for (int u = 0; u < 4; ++u) {
            px[u] = pp[u * 192 + 0];
            py[u] = pp[u * 192 + 1];
            pz[u] = pp[u * 192 + 2];
        }
#pragma unroll
        for (int u = 0; u < 4; ++u) {
            float d2 = dist2(qx, qy, qz, px[u], py[u], pz[u]);
            bool inshell = (d2 >= R_IN2) && (d2 < R_OUT2);
            unsigned long long mk = __ballot(inshell);
            if (inshell) {
                int r = cnt + __popcll(mk & below);
                if (r < SS) idxS[w][r] = j0 + u * 64 + lane;
            }
            cnt += __popcll(mk);
        }
        if (cnt >= SS) break;
    }
    if (cnt > SS) cnt = SS;
    if (lane == 0) out[bm] = (float)cnt;

    float* gout = out + BB * MM;
    int s = lane & 31, half = lane >> 5;
    int j = (s < cnt) ? idxS[w][s] : idxS[w][0];
    const float* pp = xyz + ((size_t)(b * NN) + j) * 3;
    float px = pp[0], py = pp[1], pz = pp[2];
    float v01 = half ? __fsub_rn(py, qy) : __fsub_rn(px, qx);
    gout[((size_t)(b * 67 + half) * MM + m) * SS + s] = v01;
    if (half == 0) gout[((size_t)(b * 67 + 2) * MM + m) * SS + s] = __fsub_rn(pz, qz);
#pragma unroll
    for (int k = 0; k < 32; ++k) {
        int ch = 2 * k + half;
        float v = features[((size_t)(b * CC + ch)) * NN + j];
        gout[((size_t)(b * 67 + 3 + ch) * MM + m) * SS + s] = v;
    }
}

extern "C" void kernel_launch(void* const* d_in, const int* in_sizes, int n_in,
                              void* d_out, int out_size, void* d_ws, size_t ws_size,
                              hipStream_t stream) {
    const float* xyz = (const float*)d_in[0];
    const float* new_xyz = (const float*)d_in[1];
    const float* features = (const float*)d_in[2];
    float* out = (float*)d_out;

    const size_t featT_bytes = (size_t)BB * NN * CC * 4;   // 8,388,608
    const size_t idx_bytes = (size_t)BB * MM * SS * 4;     // 524,288
    bool fast = ws_size >= featT_bytes + idx_bytes + 4;

    if (fast) {
        float* feat_t = (float*)d_ws;
        int* idx_all = (int*)((char*)d_ws + featT_bytes);
        int* maxj_cell = (int*)((char*)d_ws + featT_bytes + idx_bytes);
        scan_kernel<<<BB * MM / WPB, 64 * WPB, 0, stream>>>(xyz, new_xyz, idx_all, maxj_cell, out);
        transpose_bounded<<<2048, 256, 0, stream>>>(features, feat_t, maxj_cell);
        group_kernel<<<BB * MM / WPB, 64 * WPB, 0, stream>>>(xyz, new_xyz, feat_t, idx_all, out);
    } else {
        query_group_fallback<<<BB * MM / WPB, 64 * WPB, 0, stream>>>(xyz, new_xyz, features, out);
    }
}

// Round 11
// 104.181 us; speedup vs baseline: 1.3124x; 1.3124x over previous
//
#include <hip/hip_runtime.h>
#include <cstdint>

#define BB 2
#define NN 16384
#define MM 2048
#define CC 64
#define SS 32
#define NWAVE 8
#define SEG (NN / NWAVE)  // 2048 points per wave-segment

__device__ __forceinline__ float dist2(float qx, float qy, float qz,
                                       float px, float py, float pz) {
    // Match reference rounding: explicit mul/add, no FMA contraction.
    // Verified exact (absmax=0.0) in Rounds 4/8/9/10 — do not change.
    float dx = __fsub_rn(qx, px), dy = __fsub_rn(qy, py), dz = __fsub_rn(qz, pz);
    return __fadd_rn(__fadd_rn(__fmul_rn(dx, dx), __fmul_rn(dy, dy)), __fmul_rn(dz, dz));
}

// features (B,C,N) -> feat_t (B,N,C), tiled 32x32 through LDS.
__global__ __launch_bounds__(256) void transpose_feat(
    const float* __restrict__ f, float* __restrict__ ft) {
    __shared__ float tile[32][33];
    int bid = blockIdx.x;
    int n0 = (bid & 511) * 32;          // N/32 = 512 tiles
    int c0 = ((bid >> 9) & 1) * 32;     // C/32 = 2 tiles
    int b = bid >> 10;                  // B = 2
    int tx = threadIdx.x & 31, ty = threadIdx.x >> 5;  // (32,8)
#pragma unroll
    for (int k = 0; k < 32; k += 8)
        tile[ty + k][tx] = f[((size_t)(b * CC + c0 + ty + k)) * NN + n0 + tx];
    __syncthreads();
#pragma unroll
    for (int k = 0; k < 32; k += 8)
        ft[((size_t)(b * NN + n0 + ty + k)) * CC + c0 + tx] = tile[tx][ty + k];
}

// One block (8 waves, 512 thr) per query.
// Phase 1: segmented scan — wave s scans [s*SEG, (s+1)*SEG) with LOCAL
//   early exit at 32 matches (local rank>=32 can never reach global top-32).
// Merge: capped per-segment counts + prefix sum reproduce reference
//   slot order / cnt / first-match padding exactly.
// Phase 2: 512-thread gather: one float4 load per thread from feat_t.
// Phase 3: 512-thread store: one float4 store per thread, channel-major.
__global__ __launch_bounds__(512) void qg_kernel(
    const float* __restrict__ xyz, const float* __restrict__ new_xyz,
    const float* __restrict__ feat_t, float* __restrict__ out) {
    constexpr float R_IN2 = 0.05f * 0.05f;
    constexpr float R_OUT2 = 0.2f * 0.2f;
    __shared__ int idxL[NWAVE][SS];
    __shared__ int cS[NWAVE];
    __shared__ int idxS[SS];
    __shared__ float fbuf[SS][CC + 4];  // 16B-aligned rows (stride 68)

    int tid = threadIdx.x;
    int lane = tid & 63;
    int w = tid >> 6;  // wave id = segment id
    int bm = blockIdx.x;
    int b = bm >> 11;
    int m = bm & 2047;

    float qx = new_xyz[(size_t)bm * 3 + 0];
    float qy = new_xyz[(size_t)bm * 3 + 1];
    float qz = new_xyz[(size_t)bm * 3 + 2];

    // Phase 1: scan my segment.
    unsigned long long below = (1ull << lane) - 1ull;
    int c = 0;
    int base = w * SEG;
    for (int j0 = base; j0 < base + SEG; j0 += 256) {
        float px[4], py[4], pz[4];
        const float* pp = xyz + ((size_t)(b * NN + j0 + lane)) * 3;
#pragma unroll
        for (int u = 0; u < 4; ++u) {
            px[u] = pp[u * 192 + 0];
            py[u] = pp[u * 192 + 1];
            pz[u] = pp[u * 192 + 2];
        }
#pragma unroll
        for (int u = 0; u < 4; ++u) {
            float d2 = dist2(qx, qy, qz, px[u], py[u], pz[u]);
            bool inshell = (d2 >= R_IN2) && (d2 < R_OUT2);
            unsigned long long mk = __ballot(inshell);
            if (inshell) {
                int r = c + __popcll(mk & below);
                if (r < SS) idxL[w][r] = j0 + u * 64 + lane;
            }
            c += __popcll(mk);
        }
        if (c >= SS) break;  // wave-uniform local early exit (safe: see header)
    }
    if (c > SS) c = SS;
    if (lane == 0) cS[w] = c;
    __syncthreads();

    // Merge: threads 0..31 resolve final slot indices.
    if (tid < SS) {
        int r = tid;
        int acc = 0, pick = -1, off = 0;
#pragma unroll
        for (int s = 0; s < NWAVE; ++s) {
            int cs = cS[s];
            if (pick < 0 && r < acc + cs) { pick = s; off = r - acc; }
            acc += cs;
        }
        int cnt = acc < SS ? acc : SS;
        int j;
        if (r < cnt) {
            j = idxL[pick][off];
        } else {
            int s0 = -1;
#pragma unroll
            for (int s = 0; s < NWAVE; ++s)
                if (s0 < 0 && cS[s] > 0) s0 = s;
            j = (s0 >= 0) ? idxL[s0][0] : 0;  // first match, or 0 if none
        }
        idxS[r] = j;
        if (r == 0) out[bm] = (float)cnt;  // idx_cnt as float
    }
    __syncthreads();

    float* gout = out + BB * MM;

    // Phase 2: gather 32 slots x 64 ch — one float4 load per thread.
    {
        int sl = tid >> 4, c4 = tid & 15;
        float4 v = ((const float4*)(feat_t + ((size_t)b * NN + idxS[sl]) * CC))[c4];
        *((float4*)&fbuf[sl][c4 * 4]) = v;
    }

    // xyz channels 0..2: grouped_xyz = xyz[j] - new_xyz[m] (threads 0..95).
    if (tid < 96) {
        int ch = tid >> 5, s = tid & 31;
        int j = idxS[s];
        float pv = xyz[((size_t)(b * NN) + j) * 3 + ch];
        float qv = new_xyz[(size_t)bm * 3 + ch];
        gout[((size_t)(b * 67 + ch) * MM + m) * SS + s] = __fsub_rn(pv, qv);
    }
    __syncthreads();

    // Phase 3: feature channels — one float4 store per thread.
    {
        int ch = tid >> 3, sg = tid & 7;
        float4 v = make_float4(fbuf[sg * 4 + 0][ch], fbuf[sg * 4 + 1][ch],
                               fbuf[sg * 4 + 2][ch], fbuf[sg * 4 + 3][ch]);
        *((float4*)&gout[((size_t)(b * 67 + 3 + ch) * MM + m) * SS + sg * 4]) = v;
    }
}

// Fallback (ws too small): monolithic verified-semantics kernel, native layouts.
__global__ __launch_bounds__(256) void query_group_fallback(
    const float* __restrict__ xyz, const float* __restrict__ new_xyz,
    const float* __restrict__ features, float* __restrict__ out) {
    constexpr float R_IN2 = 0.05f * 0.05f;
    constexpr float R_OUT2 = 0.2f * 0.2f;
    __shared__ int idxS[4][SS];

    int lane = threadIdx.x & 63;
    int w = threadIdx.x >> 6;
    int bm = blockIdx.x * 4 + w;
    int b = bm >> 11;
    int m = bm & 2047;

    float qx = new_xyz[(size_t)bm * 3 + 0];
    float qy = new_xyz[(size_t)bm * 3 + 1];
    float qz = new_xyz[(size_t)bm * 3 + 2];

    if (lane == 0) idxS[w][0] = 0;

    unsigned long long below = (1ull << lane) - 1ull;
    int cnt = 0;
    for (int j0 = 0; j0 < NN; j0 += 256) {
        float px[4], py[4], pz[4];
        const float* pp = xyz + ((size_t)(b * NN + j0 + lane)) * 3;
#pragma unroll
        for (int u = 0; u < 4; ++u) {
            px[u] = pp[u * 192 + 0];
            py[u] = pp[u * 192 + 1];
            pz[u] = pp[u * 192 + 2];
        }
#pragma unroll
        for (int u = 0; u < 4; ++u) {
            float d2 = dist2(qx, qy, qz, px[u], py[u], pz[u]);
            bool inshell = (d2 >= R_IN2) && (d2 < R_OUT2);
            unsigned long long mk = __ballot(inshell);
            if (inshell) {
                int r = cnt + __popcll(mk & below);
                if (r < SS) idxS[w][r] = j0 + u * 64 + lane;
            }
            cnt += __popcll(mk);
        }
        if (cnt >= SS) break;
    }
    if (cnt > SS) cnt = SS;
    if (lane == 0) out[bm] = (float)cnt;

    float* gout = out + BB * MM;
    int s = lane & 31, half = lane >> 5;
    int j = (s < cnt) ? idxS[w][s] : idxS[w][0];
    const float* pp = xyz + ((size_t)(b * NN) + j) * 3;
    float px = pp[0], py = pp[1], pz = pp[2];
    float v01 = half ? __fsub_rn(py, qy) : __fsub_rn(px, qx);
    gout[((size_t)(b * 67 + half) * MM + m) * SS + s] = v01;
    if (half == 0) gout[((size_t)(b * 67 + 2) * MM + m) * SS + s] = __fsub_rn(pz, qz);
#pragma unroll
    for (int k = 0; k < 32; ++k) {
        int ch = 2 * k + half;
        float v = features[((size_t)(b * CC + ch)) * NN + j];
        gout[((size_t)(b * 67 + 3 + ch) * MM + m) * SS + s] = v;
    }
}

extern "C" void kernel_launch(void* const* d_in, const int* in_sizes, int n_in,
                              void* d_out, int out_size, void* d_ws, size_t ws_size,
                              hipStream_t stream) {
    const float* xyz = (const float*)d_in[0];
    const float* new_xyz = (const float*)d_in[1];
    const float* features = (const float*)d_in[2];
    float* out = (float*)d_out;

    const size_t featT_bytes = (size_t)BB * NN * CC * 4;  // 8,388,608
    bool fast = ws_size >= featT_bytes;

    if (fast) {
        float* feat_t = (float*)d_ws;
        transpose_feat<<<2048, 256, 0, stream>>>(features, feat_t);
        qg_kernel<<<BB * MM, 512, 0, stream>>>(xyz, new_xyz, feat_t, out);
    } else {
        query_group_fallback<<<BB * MM / 4, 256, 0, stream>>>(xyz, new_xyz, features, out);
    }
}